// Round 9
// baseline (395.086 us; speedup 1.0000x reference)
//
#include <hip/hip_runtime.h>
#include <stdint.h>

// EdgeNetwork per-edge MLP — round 16: clean occupancy test (r13 + bound 4).
//  r15 post-mortem: r14+bound4 NaN'd even though VGPR=80 < 128 cap — the
//  bound re-drives scheduling/allocation, and the only scheduling-sensitive
//  component is the hand-fused v_add_f32_dpp asm (r8 proved bound4+spills
//  alone doesn't corrupt). Discipline: stop combining fragile asm with
//  allocation changes. r16 = r13 EXACTLY (builtin update_dpp only, zero
//  hand-scheduled VALU asm; passed at 164us) + __launch_bounds__(256,4).
//  Outcomes: pass+fast -> occupancy confirmed, re-add VALU cuts carefully;
//  pass+164 -> occupancy not the lever, pivot; spills/NaN -> bound4 closed.

#define TPB 256
#define NEG_SLOPE 0.1f
#define LN_EPS    1e-5f

typedef __attribute__((ext_vector_type(8))) short short8;   // 8 bf16 (4 VGPR)
typedef __attribute__((ext_vector_type(4))) float f32x4;    // 4 f32

__device__ __forceinline__ uint32_t fb(float x) {
  union { float f; uint32_t u; } c; c.f = x; return c.u;
}
__device__ __forceinline__ float bf(uint32_t x) {
  union { uint32_t u; float f; } c; c.u = x; return c.f;
}
// ---- f32 pair -> packed bf16 (RNE), 1 instr; src0 -> low half ----
__device__ __forceinline__ uint32_t cvtpk(float a, float b) {
  uint32_t r; asm("v_cvt_pk_bf16_f32 %0, %1, %2" : "=v"(r) : "v"(a), "v"(b));
  return r;
}
__device__ __forceinline__ short8 cvt8(f32x4 a, f32x4 b) {
  union { short8 s; uint32_t u[4]; } r;
  r.u[0] = cvtpk(a[0], a[1]);
  r.u[1] = cvtpk(a[2], a[3]);
  r.u[2] = cvtpk(b[0], b[1]);
  r.u[3] = cvtpk(b[2], b[3]);
  return r.s;
}
__device__ __forceinline__ short bf16rne(float x) {   // staging (one-time)
  uint32_t u = fb(x);
  return (short)((u + 0x7fffu + ((u >> 16) & 1u)) >> 16);
}

// DPP rotation-allreduce across each row of 16 lanes (builtin form — the
// compiler inserts required hazard waits; proven correct rounds 7-13).
template <int CTRL>
__device__ __forceinline__ float dppadd(float v) {
  int r = __builtin_amdgcn_update_dpp(0, (int)fb(v), CTRL, 0xf, 0xf, true);
  return v + bf((uint32_t)r);
}
__device__ __forceinline__ float rowsum16(float v) {
  v = dppadd<0x121>(v);   // row_ror:1
  v = dppadd<0x122>(v);   // row_ror:2
  v = dppadd<0x124>(v);   // row_ror:4
  v = dppadd<0x128>(v);   // row_ror:8
  return v;
}
__device__ __forceinline__ void redsum16(f32x4& v) {
  #pragma unroll
  for (int c = 0; c < 4; ++c) v[c] = rowsum16(v[c]);
}

// LN stats over 64 features held as acc[4] (cols ln+16*jt, rows quad*4+r).
// Plain vector math; compiler packs where profitable. NO hand asm.
__device__ __forceinline__ void lnstats(const f32x4& a0, const f32x4& a1,
                                        const f32x4& a2, const f32x4& a3,
                                        f32x4& mu, f32x4& rs) {
  f32x4 sv = a0 + a1 + a2 + a3;
  f32x4 qv = a0 * a0 + a1 * a1 + a2 * a2 + a3 * a3;
  redsum16(sv);
  redsum16(qv);
  mu = sv * (1.f / 64.f);
  f32x4 var = qv * (1.f / 64.f) - mu * mu;
  rs[0] = rsqrtf(var[0] + LN_EPS); rs[1] = rsqrtf(var[1] + LN_EPS);
  rs[2] = rsqrtf(var[2] + LN_EPS); rs[3] = rsqrtf(var[3] + LN_EPS);
}

// LDS strides (shorts): must be multiples of 8 shorts (16B) for b128 rows.
#define SW1 168
#define SW2 72

__global__ __launch_bounds__(TPB, 4)
void edge_mlp_mfma(const float* __restrict__ nf, const int* __restrict__ ei,
                   const float* __restrict__ ea,
                   const float* __restrict__ W1, const float* __restrict__ b1,
                   const float* __restrict__ g1, const float* __restrict__ be1,
                   const float* __restrict__ W2, const float* __restrict__ b2,
                   const float* __restrict__ g2, const float* __restrict__ be2,
                   const float* __restrict__ W3, const float* __restrict__ b3,
                   float* __restrict__ out, int E, int ntiles) {
  __shared__ short W1T[64 * SW1];      // [n][k], k 0..159 (144 real + 16 zero)
  __shared__ short W2T[64 * SW2];      // [n][k]
  __shared__ short HB[4][16 * SW2];    // per-wave h1 tile (16 edges x 64)

  const int tid  = threadIdx.x;
  const int lane = tid & 63;
  const int wv   = tid >> 6;
  const int ln   = lane & 15;
  const int quad = lane >> 4;

  // ---- Stage W1^T, W2^T as bf16 into LDS ----
  for (int i = tid; i < 9216; i += TPB) {
    int n = i & 63, k = i >> 6;
    W1T[n * SW1 + k] = bf16rne(W1[k * 64 + n]);
  }
  for (int i = tid; i < 1024; i += TPB) {            // zero-pad k in [144,160)
    int n = i & 63, k = 144 + (i >> 6);
    W1T[n * SW1 + k] = 0;
  }
  for (int i = tid; i < 4096; i += TPB) {
    int n = i & 63, k = i >> 6;
    W2T[n * SW2 + k] = bf16rne(W2[k * 64 + n]);
  }
  __syncthreads();   // the ONLY block barrier

  // ---- Per-lane n-indexed params (n = ln + 16*jt) ----
  float b1v[4], g1v[4], be1v[4], b2v[4], g2v[4], be2v[4], W3v[4];
  #pragma unroll
  for (int jt = 0; jt < 4; ++jt) {
    int n = ln + 16 * jt;
    b1v[jt] = b1[n];  g1v[jt] = g1[n];  be1v[jt] = be1[n];
    b2v[jt] = b2[n];  g2v[jt] = g2[n];  be2v[jt] = be2[n];
    W3v[jt] = W3[n];
  }
  const float b3s = b3[0];

  // int64-vs-int32 index sniff (validated rounds 3-14)
  const bool idx64 = (__ballot(ei[2 * lane + 1] == 0) == ~0ull);

  // ---- Indices: current tile (sI/dI) and next tile (sN/dN) ----
  int sI[4], dI[4], sN[4], dN[4];
  {
    const int eb0 = blockIdx.x * 256 + wv * 64;
    #pragma unroll
    for (int mt = 0; mt < 4; ++mt) {
      int el = eb0 + mt * 16 + ln;
      int ec = el < E ? el : E - 1;
      if (idx64) { sI[mt] = ei[2 * ec]; dI[mt] = ei[2 * (E + ec)]; }
      else       { sI[mt] = ei[ec];     dI[mt] = ei[E + ec]; }
      sN[mt] = sI[mt]; dN[mt] = dI[mt];   // safe defaults for the last tile
    }
  }

  // ---- Gather in-flight buffer (one mt's worth) ----
  f32x4 raw[10];
  auto issue = [&](int s, int d, int el) {
    int ec = el < E ? el : E - 1;
    const float* sp = nf + (size_t)s * 64 + quad * 8;
    const float* dp = nf + (size_t)d * 64 + quad * 8;
    const float* ap = ea + (size_t)ec * 16 + (quad & 1) * 8;
    raw[0] = *(const f32x4*)sp;        raw[1] = *(const f32x4*)(sp + 4);
    raw[2] = *(const f32x4*)(sp + 32); raw[3] = *(const f32x4*)(sp + 36);
    raw[4] = *(const f32x4*)dp;        raw[5] = *(const f32x4*)(dp + 4);
    raw[6] = *(const f32x4*)(dp + 32); raw[7] = *(const f32x4*)(dp + 36);
    raw[8] = *(const f32x4*)ap;        raw[9] = *(const f32x4*)(ap + 4);
  };

  // prologue: first mt's gather in flight
  issue(sI[0], dI[0], blockIdx.x * 256 + wv * 64 + ln);

  for (int tile = blockIdx.x; tile < ntiles; tile += gridDim.x) {
    const int ebase = tile * 256 + wv * 64;

    #pragma unroll
    for (int mt = 0; mt < 4; ++mt) {
      // ---- convert landed gather to bf16 A-fragments (frees raw[]) ----
      short8 afr[5];
      afr[0] = cvt8(raw[0], raw[1]);
      afr[1] = cvt8(raw[2], raw[3]);
      afr[2] = cvt8(raw[4], raw[5]);
      afr[3] = cvt8(raw[6], raw[7]);
      afr[4] = cvt8(raw[8], raw[9]);   // k>=144 lanes: B rows zero, value moot

      // ---- Layer 1: 20 MFMAs (bias pre-folded into acc init) ----
      f32x4 acc[4];                    // [jt]
      #pragma unroll
      for (int jt = 0; jt < 4; ++jt) acc[jt] = (f32x4)(b1v[jt]);

      #pragma unroll
      for (int t = 0; t < 5; ++t)
        #pragma unroll
        for (int jt = 0; jt < 4; ++jt) {
          short8 bfr = *(const short8*)&W1T[(jt * 16 + ln) * SW1 + t * 32 + quad * 8];
          acc[jt] = __builtin_amdgcn_mfma_f32_16x16x32_bf16(
              afr[t], bfr, acc[jt], 0, 0, 0);
        }

      // ---- Prefetch next tile's indices (consumed at mt==3) ----
      if (mt == 1) {
        int ntile = tile + gridDim.x;
        if (ntile < ntiles) {
          const int nb = ntile * 256 + wv * 64;
          #pragma unroll
          for (int m2 = 0; m2 < 4; ++m2) {
            int el = nb + m2 * 16 + ln;
            int ec = el < E ? el : E - 1;
            if (idx64) { sN[m2] = ei[2 * ec]; dN[m2] = ei[2 * (E + ec)]; }
            else       { sN[m2] = ei[ec];     dN[m2] = ei[E + ec]; }
          }
        }
      }

      // ---- Issue next mt's gather: latency hides under this epilogue ----
      if (mt < 3) issue(sI[mt + 1], dI[mt + 1], ebase + (mt + 1) * 16 + ln);
      else        issue(sN[0], dN[0], (tile + (int)gridDim.x) * 256 + wv * 64 + ln);

      // ---- Epilogue (wave-private; DPP reductions, no barriers) ----
      f32x4 mu, rs;
      lnstats(acc[0], acc[1], acc[2], acc[3], mu, rs);

      #pragma unroll
      for (int jt = 0; jt < 4; ++jt)
        #pragma unroll
        for (int r = 0; r < 4; ++r) {
          float h = (acc[jt][r] - mu[r]) * rs[r] * g1v[jt] + be1v[jt];
          h = fmaxf(h, NEG_SLOPE * h);
          HB[wv][(quad * 4 + r) * SW2 + ln + 16 * jt] = (short)cvtpk(h, h);
        }
      // wave-private handoff: DS in-order per wave; drain writes then read
      asm volatile("s_waitcnt lgkmcnt(0)" ::: "memory");

      f32x4 acc2[4];
      #pragma unroll
      for (int jt = 0; jt < 4; ++jt) acc2[jt] = (f32x4)(b2v[jt]);
      #pragma unroll
      for (int t2 = 0; t2 < 2; ++t2) {
        short8 a2 = *(const short8*)&HB[wv][ln * SW2 + t2 * 32 + quad * 8];
        #pragma unroll
        for (int jt = 0; jt < 4; ++jt) {
          short8 w2f = *(const short8*)&W2T[(jt * 16 + ln) * SW2 + t2 * 32 + quad * 8];
          acc2[jt] = __builtin_amdgcn_mfma_f32_16x16x32_bf16(
              a2, w2f, acc2[jt], 0, 0, 0);
        }
      }

      f32x4 mu2, rs2;
      lnstats(acc2[0], acc2[1], acc2[2], acc2[3], mu2, rs2);

      f32x4 po = (f32x4)0.f;
      #pragma unroll
      for (int jt = 0; jt < 4; ++jt)
        #pragma unroll
        for (int r = 0; r < 4; ++r) {
          float h = (acc2[jt][r] - mu2[r]) * rs2[r] * g2v[jt] + be2v[jt];
          h = fmaxf(h, NEG_SLOPE * h);
          po[r] = fmaf(h, W3v[jt], po[r]);
        }
      redsum16(po);

      if (ln < 4) {       // lanes 0-3 of each quad store edges quad*4 + ln
        int e = ebase + mt * 16 + quad * 4 + ln;
        if (e < E) {
          float v = (ln == 0) ? po[0] : (ln == 1) ? po[1]
                  : (ln == 2) ? po[2] : po[3];
          out[e] = v + b3s;
        }
      }
    }

    // rotate next-tile indices into place
    #pragma unroll
    for (int m2 = 0; m2 < 4; ++m2) { sI[m2] = sN[m2]; dI[m2] = dN[m2]; }
  }
}

extern "C" void kernel_launch(void* const* d_in, const int* in_sizes, int n_in,
                              void* d_out, int out_size, void* d_ws, size_t ws_size,
                              hipStream_t stream) {
  const float* nf = (const float*)d_in[0];
  const int*   ei = (const int*)d_in[1];
  const float* ea = (const float*)d_in[2];

  const int E = out_size;
  const int ntiles = (E + 255) / 256;
  const int blocks = ntiles < 2048 ? ntiles : 2048;

  edge_mlp_mfma<<<blocks, TPB, 0, stream>>>(
      nf, ei, ea,
      (const float*)d_in[3],  (const float*)d_in[4],
      (const float*)d_in[5],  (const float*)d_in[6],
      (const float*)d_in[7],  (const float*)d_in[8],
      (const float*)d_in[9],  (const float*)d_in[10],
      (const float*)d_in[11], (const float*)d_in[12],
      (float*)d_out, E, ntiles);
}

// Round 10
// 291.334 us; speedup vs baseline: 1.3561x; 1.3561x over previous
//
#include <hip/hip_runtime.h>
#include <stdint.h>

// EdgeNetwork per-edge MLP — round 17: remove the per-mt lgkmcnt(0) walls.
//  r16 post-mortem: bound 4 CLOSED — allocator splits 128 as ~64 VGPR+64 AGPR
//  and spills (r8 & r16 identical signature: VGPR=64, WRITE ~150MB, 259us).
//  Bound 3 / 164us is the operating point; occupancy not buyable.
//  r17 theory: both pipes ~50% busy -> serial-chain-bound. The per-mt
//  asm volatile lgkmcnt(0) + "memory" clobber drains the whole DS queue AND
//  forbids hoisting mt+1's 20 independent W1T reads above the epilogue —
//  a 4x-per-tile DS-pipeline restart. It is unnecessary: DS ops from one
//  wave execute IN ORDER (lgkmcnt governs data-return visibility, not LDS
//  ordering); the HB write->read RAW is safe in program order, and the
//  reads' data use gets a compiler-inserted counted lgkmcnt before the MFMA.
//  r17 = r13 exactly (robust base: builtin update_dpp, no fragile asm,
//  bound 3) minus the 4 drains. Falsifier: finite O(1) error -> in-order-DS
//  assumption wrong -> restore drains permanently.

#define TPB 256
#define NEG_SLOPE 0.1f
#define LN_EPS    1e-5f

typedef __attribute__((ext_vector_type(8))) short short8;   // 8 bf16 (4 VGPR)
typedef __attribute__((ext_vector_type(4))) float f32x4;    // 4 f32

__device__ __forceinline__ uint32_t fb(float x) {
  union { float f; uint32_t u; } c; c.f = x; return c.u;
}
__device__ __forceinline__ float bf(uint32_t x) {
  union { uint32_t u; float f; } c; c.u = x; return c.f;
}
// ---- f32 pair -> packed bf16 (RNE), 1 instr; src0 -> low half ----
__device__ __forceinline__ uint32_t cvtpk(float a, float b) {
  uint32_t r; asm("v_cvt_pk_bf16_f32 %0, %1, %2" : "=v"(r) : "v"(a), "v"(b));
  return r;
}
__device__ __forceinline__ short8 cvt8(f32x4 a, f32x4 b) {
  union { short8 s; uint32_t u[4]; } r;
  r.u[0] = cvtpk(a[0], a[1]);
  r.u[1] = cvtpk(a[2], a[3]);
  r.u[2] = cvtpk(b[0], b[1]);
  r.u[3] = cvtpk(b[2], b[3]);
  return r.s;
}
__device__ __forceinline__ short bf16rne(float x) {   // staging (one-time)
  uint32_t u = fb(x);
  return (short)((u + 0x7fffu + ((u >> 16) & 1u)) >> 16);
}

// DPP rotation-allreduce across each row of 16 lanes (builtin form — the
// compiler inserts required hazard waits; proven correct rounds 7-16).
template <int CTRL>
__device__ __forceinline__ float dppadd(float v) {
  int r = __builtin_amdgcn_update_dpp(0, (int)fb(v), CTRL, 0xf, 0xf, true);
  return v + bf((uint32_t)r);
}
__device__ __forceinline__ float rowsum16(float v) {
  v = dppadd<0x121>(v);   // row_ror:1
  v = dppadd<0x122>(v);   // row_ror:2
  v = dppadd<0x124>(v);   // row_ror:4
  v = dppadd<0x128>(v);   // row_ror:8
  return v;
}
__device__ __forceinline__ void redsum16(f32x4& v) {
  #pragma unroll
  for (int c = 0; c < 4; ++c) v[c] = rowsum16(v[c]);
}

// LN stats over 64 features held as acc[4] (cols ln+16*jt, rows quad*4+r).
__device__ __forceinline__ void lnstats(const f32x4& a0, const f32x4& a1,
                                        const f32x4& a2, const f32x4& a3,
                                        f32x4& mu, f32x4& rs) {
  f32x4 sv = a0 + a1 + a2 + a3;
  f32x4 qv = a0 * a0 + a1 * a1 + a2 * a2 + a3 * a3;
  redsum16(sv);
  redsum16(qv);
  mu = sv * (1.f / 64.f);
  f32x4 var = qv * (1.f / 64.f) - mu * mu;
  rs[0] = rsqrtf(var[0] + LN_EPS); rs[1] = rsqrtf(var[1] + LN_EPS);
  rs[2] = rsqrtf(var[2] + LN_EPS); rs[3] = rsqrtf(var[3] + LN_EPS);
}

// LDS strides (shorts): must be multiples of 8 shorts (16B) for b128 rows.
#define SW1 168
#define SW2 72

__global__ __launch_bounds__(TPB, 3)
void edge_mlp_mfma(const float* __restrict__ nf, const int* __restrict__ ei,
                   const float* __restrict__ ea,
                   const float* __restrict__ W1, const float* __restrict__ b1,
                   const float* __restrict__ g1, const float* __restrict__ be1,
                   const float* __restrict__ W2, const float* __restrict__ b2,
                   const float* __restrict__ g2, const float* __restrict__ be2,
                   const float* __restrict__ W3, const float* __restrict__ b3,
                   float* __restrict__ out, int E, int ntiles) {
  __shared__ short W1T[64 * SW1];      // [n][k], k 0..159 (144 real + 16 zero)
  __shared__ short W2T[64 * SW2];      // [n][k]
  __shared__ short HB[4][16 * SW2];    // per-wave h1 tile (16 edges x 64)

  const int tid  = threadIdx.x;
  const int lane = tid & 63;
  const int wv   = tid >> 6;
  const int ln   = lane & 15;
  const int quad = lane >> 4;

  // ---- Stage W1^T, W2^T as bf16 into LDS ----
  for (int i = tid; i < 9216; i += TPB) {
    int n = i & 63, k = i >> 6;
    W1T[n * SW1 + k] = bf16rne(W1[k * 64 + n]);
  }
  for (int i = tid; i < 1024; i += TPB) {            // zero-pad k in [144,160)
    int n = i & 63, k = 144 + (i >> 6);
    W1T[n * SW1 + k] = 0;
  }
  for (int i = tid; i < 4096; i += TPB) {
    int n = i & 63, k = i >> 6;
    W2T[n * SW2 + k] = bf16rne(W2[k * 64 + n]);
  }
  __syncthreads();   // the ONLY block barrier

  // ---- Per-lane n-indexed params (n = ln + 16*jt) ----
  float b1v[4], g1v[4], be1v[4], b2v[4], g2v[4], be2v[4], W3v[4];
  #pragma unroll
  for (int jt = 0; jt < 4; ++jt) {
    int n = ln + 16 * jt;
    b1v[jt] = b1[n];  g1v[jt] = g1[n];  be1v[jt] = be1[n];
    b2v[jt] = b2[n];  g2v[jt] = g2[n];  be2v[jt] = be2[n];
    W3v[jt] = W3[n];
  }
  const float b3s = b3[0];

  // int64-vs-int32 index sniff (validated rounds 3-16)
  const bool idx64 = (__ballot(ei[2 * lane + 1] == 0) == ~0ull);

  // ---- Indices: current tile (sI/dI) and next tile (sN/dN) ----
  int sI[4], dI[4], sN[4], dN[4];
  {
    const int eb0 = blockIdx.x * 256 + wv * 64;
    #pragma unroll
    for (int mt = 0; mt < 4; ++mt) {
      int el = eb0 + mt * 16 + ln;
      int ec = el < E ? el : E - 1;
      if (idx64) { sI[mt] = ei[2 * ec]; dI[mt] = ei[2 * (E + ec)]; }
      else       { sI[mt] = ei[ec];     dI[mt] = ei[E + ec]; }
      sN[mt] = sI[mt]; dN[mt] = dI[mt];   // safe defaults for the last tile
    }
  }

  // ---- Gather in-flight buffer (one mt's worth) ----
  f32x4 raw[10];
  auto issue = [&](int s, int d, int el) {
    int ec = el < E ? el : E - 1;
    const float* sp = nf + (size_t)s * 64 + quad * 8;
    const float* dp = nf + (size_t)d * 64 + quad * 8;
    const float* ap = ea + (size_t)ec * 16 + (quad & 1) * 8;
    raw[0] = *(const f32x4*)sp;        raw[1] = *(const f32x4*)(sp + 4);
    raw[2] = *(const f32x4*)(sp + 32); raw[3] = *(const f32x4*)(sp + 36);
    raw[4] = *(const f32x4*)dp;        raw[5] = *(const f32x4*)(dp + 4);
    raw[6] = *(const f32x4*)(dp + 32); raw[7] = *(const f32x4*)(dp + 36);
    raw[8] = *(const f32x4*)ap;        raw[9] = *(const f32x4*)(ap + 4);
  };

  // prologue: first mt's gather in flight
  issue(sI[0], dI[0], blockIdx.x * 256 + wv * 64 + ln);

  for (int tile = blockIdx.x; tile < ntiles; tile += gridDim.x) {
    const int ebase = tile * 256 + wv * 64;

    #pragma unroll
    for (int mt = 0; mt < 4; ++mt) {
      // ---- convert landed gather to bf16 A-fragments (frees raw[]) ----
      short8 afr[5];
      afr[0] = cvt8(raw[0], raw[1]);
      afr[1] = cvt8(raw[2], raw[3]);
      afr[2] = cvt8(raw[4], raw[5]);
      afr[3] = cvt8(raw[6], raw[7]);
      afr[4] = cvt8(raw[8], raw[9]);   // k>=144 lanes: B rows zero, value moot

      // ---- Layer 1: 20 MFMAs (bias pre-folded into acc init) ----
      f32x4 acc[4];                    // [jt]
      #pragma unroll
      for (int jt = 0; jt < 4; ++jt) acc[jt] = (f32x4)(b1v[jt]);

      #pragma unroll
      for (int t = 0; t < 5; ++t)
        #pragma unroll
        for (int jt = 0; jt < 4; ++jt) {
          short8 bfr = *(const short8*)&W1T[(jt * 16 + ln) * SW1 + t * 32 + quad * 8];
          acc[jt] = __builtin_amdgcn_mfma_f32_16x16x32_bf16(
              afr[t], bfr, acc[jt], 0, 0, 0);
        }

      // ---- Prefetch next tile's indices (consumed at mt==3) ----
      if (mt == 1) {
        int ntile = tile + gridDim.x;
        if (ntile < ntiles) {
          const int nb = ntile * 256 + wv * 64;
          #pragma unroll
          for (int m2 = 0; m2 < 4; ++m2) {
            int el = nb + m2 * 16 + ln;
            int ec = el < E ? el : E - 1;
            if (idx64) { sN[m2] = ei[2 * ec]; dN[m2] = ei[2 * (E + ec)]; }
            else       { sN[m2] = ei[ec];     dN[m2] = ei[E + ec]; }
          }
        }
      }

      // ---- Issue next mt's gather: latency hides under this epilogue ----
      if (mt < 3) issue(sI[mt + 1], dI[mt + 1], ebase + (mt + 1) * 16 + ln);
      else        issue(sN[0], dN[0], (tile + (int)gridDim.x) * 256 + wv * 64 + ln);

      // ---- Epilogue (wave-private; DPP reductions, no barriers) ----
      f32x4 mu, rs;
      lnstats(acc[0], acc[1], acc[2], acc[3], mu, rs);

      #pragma unroll
      for (int jt = 0; jt < 4; ++jt)
        #pragma unroll
        for (int r = 0; r < 4; ++r) {
          float h = (acc[jt][r] - mu[r]) * rs[r] * g1v[jt] + be1v[jt];
          h = fmaxf(h, NEG_SLOPE * h);
          HB[wv][(quad * 4 + r) * SW2 + ln + 16 * jt] = (short)cvtpk(h, h);
        }
      // NO lgkmcnt(0) drain: DS ops from one wave execute in order, so the
      // HB b128 reads below see the writes above; the reads' data use gets a
      // compiler-inserted counted lgkmcnt before the consuming MFMA. Removing
      // the asm wall lets the scheduler hoist mt+1's W1T reads across this
      // epilogue (they're a provably-distinct LDS object).

      f32x4 acc2[4];
      #pragma unroll
      for (int jt = 0; jt < 4; ++jt) acc2[jt] = (f32x4)(b2v[jt]);
      #pragma unroll
      for (int t2 = 0; t2 < 2; ++t2) {
        short8 a2 = *(const short8*)&HB[wv][ln * SW2 + t2 * 32 + quad * 8];
        #pragma unroll
        for (int jt = 0; jt < 4; ++jt) {
          short8 w2f = *(const short8*)&W2T[(jt * 16 + ln) * SW2 + t2 * 32 + quad * 8];
          acc2[jt] = __builtin_amdgcn_mfma_f32_16x16x32_bf16(
              a2, w2f, acc2[jt], 0, 0, 0);
        }
      }

      f32x4 mu2, rs2;
      lnstats(acc2[0], acc2[1], acc2[2], acc2[3], mu2, rs2);

      f32x4 po = (f32x4)0.f;
      #pragma unroll
      for (int jt = 0; jt < 4; ++jt)
        #pragma unroll
        for (int r = 0; r < 4; ++r) {
          float h = (acc2[jt][r] - mu2[r]) * rs2[r] * g2v[jt] + be2v[jt];
          h = fmaxf(h, NEG_SLOPE * h);
          po[r] = fmaf(h, W3v[jt], po[r]);
        }
      redsum16(po);

      if (ln < 4) {       // lanes 0-3 of each quad store edges quad*4 + ln
        int e = ebase + mt * 16 + quad * 4 + ln;
        if (e < E) {
          float v = (ln == 0) ? po[0] : (ln == 1) ? po[1]
                  : (ln == 2) ? po[2] : po[3];
          out[e] = v + b3s;
        }
      }
    }

    // rotate next-tile indices into place
    #pragma unroll
    for (int m2 = 0; m2 < 4; ++m2) { sI[m2] = sN[m2]; dI[m2] = dN[m2]; }
  }
}

extern "C" void kernel_launch(void* const* d_in, const int* in_sizes, int n_in,
                              void* d_out, int out_size, void* d_ws, size_t ws_size,
                              hipStream_t stream) {
  const float* nf = (const float*)d_in[0];
  const int*   ei = (const int*)d_in[1];
  const float* ea = (const float*)d_in[2];

  const int E = out_size;
  const int ntiles = (E + 255) / 256;
  const int blocks = ntiles < 2048 ? ntiles : 2048;

  edge_mlp_mfma<<<blocks, TPB, 0, stream>>>(
      nf, ei, ea,
      (const float*)d_in[3],  (const float*)d_in[4],
      (const float*)d_in[5],  (const float*)d_in[6],
      (const float*)d_in[7],  (const float*)d_in[8],
      (const float*)d_in[9],  (const float*)d_in[10],
      (const float*)d_in[11], (const float*)d_in[12],
      (float*)d_out, E, ntiles);
}

// Round 11
// 287.462 us; speedup vs baseline: 1.3744x; 1.0135x over previous
//
#include <hip/hip_runtime.h>
#include <stdint.h>

// EdgeNetwork per-edge MLP — round 18: live-set shrink + 4 blocks/CU.
//  Ledger: VALU cut (r14) null; DS-wall removal (r17) null; bound-4 spills
//  (r8/r16, live ~150 vs 128 cap) — but r16 proved 4 blocks/CU ARE resident
//  (42% occ). Kernel is latency-bound (~35% issue util/wave, 3 waves/SIMD).
//  r18 shrinks the live set so bound 4 fits:
//   (a) nf pre-converted to bf16 in d_ws (pre-kernel, ~4us): gather loads
//       A-fragments DIRECTLY (short8) — 16 fewer cvt_pk/mt, flight regs
//       40->24, nf L2 footprint 12.8->6.4MB (less XCD-L2 thrash)
//   (b) gamma/beta packed as bf16 pairs (16->8 regs)
//   (c) double-buffered gather banks (no register copies)
//   -> peak live ~116 < 128 -> __launch_bounds__(256,4), 16 waves/CU.
//  Falsifier: WRITE_SIZE >> 20MB = spills -> revert to bound 3.
//  Fallback: ws too small -> r17 kernel unchanged.

#define TPB 256
#define NEG_SLOPE 0.1f
#define LN_EPS    1e-5f

typedef __attribute__((ext_vector_type(8))) short short8;   // 8 bf16 (4 VGPR)
typedef __attribute__((ext_vector_type(4))) float f32x4;    // 4 f32

__device__ __forceinline__ uint32_t fb(float x) {
  union { float f; uint32_t u; } c; c.f = x; return c.u;
}
__device__ __forceinline__ float bf(uint32_t x) {
  union { uint32_t u; float f; } c; c.u = x; return c.f;
}
// ---- f32 pair -> packed bf16 (RNE), 1 instr; src0 -> low half ----
__device__ __forceinline__ uint32_t cvtpk(float a, float b) {
  uint32_t r; asm("v_cvt_pk_bf16_f32 %0, %1, %2" : "=v"(r) : "v"(a), "v"(b));
  return r;
}
__device__ __forceinline__ short8 cvt8(f32x4 a, f32x4 b) {
  union { short8 s; uint32_t u[4]; } r;
  r.u[0] = cvtpk(a[0], a[1]);
  r.u[1] = cvtpk(a[2], a[3]);
  r.u[2] = cvtpk(b[0], b[1]);
  r.u[3] = cvtpk(b[2], b[3]);
  return r.s;
}
__device__ __forceinline__ short bf16rne(float x) {   // staging (one-time)
  uint32_t u = fb(x);
  return (short)((u + 0x7fffu + ((u >> 16) & 1u)) >> 16);
}

// DPP rotation-allreduce across each row of 16 lanes (builtin form — the
// compiler inserts required hazard waits; proven correct rounds 7-17).
template <int CTRL>
__device__ __forceinline__ float dppadd(float v) {
  int r = __builtin_amdgcn_update_dpp(0, (int)fb(v), CTRL, 0xf, 0xf, true);
  return v + bf((uint32_t)r);
}
__device__ __forceinline__ float rowsum16(float v) {
  v = dppadd<0x121>(v);   // row_ror:1
  v = dppadd<0x122>(v);   // row_ror:2
  v = dppadd<0x124>(v);   // row_ror:4
  v = dppadd<0x128>(v);   // row_ror:8
  return v;
}
__device__ __forceinline__ void redsum16(f32x4& v) {
  #pragma unroll
  for (int c = 0; c < 4; ++c) v[c] = rowsum16(v[c]);
}

__device__ __forceinline__ void lnstats(const f32x4& a0, const f32x4& a1,
                                        const f32x4& a2, const f32x4& a3,
                                        f32x4& mu, f32x4& rs) {
  f32x4 sv = a0 + a1 + a2 + a3;
  f32x4 qv = a0 * a0 + a1 * a1 + a2 * a2 + a3 * a3;
  redsum16(sv);
  redsum16(qv);
  mu = sv * (1.f / 64.f);
  f32x4 var = qv * (1.f / 64.f) - mu * mu;
  rs[0] = rsqrtf(var[0] + LN_EPS); rs[1] = rsqrtf(var[1] + LN_EPS);
  rs[2] = rsqrtf(var[2] + LN_EPS); rs[3] = rsqrtf(var[3] + LN_EPS);
}

// LDS strides (shorts): must be multiples of 8 shorts (16B) for b128 rows.
#define SW1 168
#define SW2 72

// ---- pre-kernel: nf f32 -> bf16 workspace (one-time, ~4us) ----
__global__ __launch_bounds__(256)
void cvt_nf(const float* __restrict__ nf, unsigned short* __restrict__ nfb,
            int n) {
  int i = (blockIdx.x * 256 + threadIdx.x) * 8;
  if (i < n) {
    f32x4 a = *(const f32x4*)(nf + i);
    f32x4 b = *(const f32x4*)(nf + i + 4);
    union { short8 s; uint32_t u[4]; } r;
    r.u[0] = cvtpk(a[0], a[1]); r.u[1] = cvtpk(a[2], a[3]);
    r.u[2] = cvtpk(b[0], b[1]); r.u[3] = cvtpk(b[2], b[3]);
    *(short8*)(nfb + i) = r.s;
  }
}

// ================= bf16-gather main kernel (bound 4) =================
__global__ __launch_bounds__(TPB, 4)
void edge_mlp_mfma_bf(const unsigned short* __restrict__ nfb,
                      const int* __restrict__ ei,
                      const float* __restrict__ ea,
                      const float* __restrict__ W1, const float* __restrict__ b1,
                      const float* __restrict__ g1, const float* __restrict__ be1,
                      const float* __restrict__ W2, const float* __restrict__ b2,
                      const float* __restrict__ g2, const float* __restrict__ be2,
                      const float* __restrict__ W3, const float* __restrict__ b3,
                      float* __restrict__ out, int E, int ntiles) {
  __shared__ short W1T[64 * SW1];
  __shared__ short W2T[64 * SW2];
  __shared__ short HB[4][16 * SW2];

  const int tid  = threadIdx.x;
  const int lane = tid & 63;
  const int wv   = tid >> 6;
  const int ln   = lane & 15;
  const int quad = lane >> 4;

  for (int i = tid; i < 9216; i += TPB) {
    int n = i & 63, k = i >> 6;
    W1T[n * SW1 + k] = bf16rne(W1[k * 64 + n]);
  }
  for (int i = tid; i < 1024; i += TPB) {
    int n = i & 63, k = 144 + (i >> 6);
    W1T[n * SW1 + k] = 0;
  }
  for (int i = tid; i < 4096; i += TPB) {
    int n = i & 63, k = i >> 6;
    W2T[n * SW2 + k] = bf16rne(W2[k * 64 + n]);
  }
  __syncthreads();   // the ONLY block barrier

  // ---- params: biases f32; gamma/beta packed bf16 (hi=g, lo=be) ----
  float b1v[4], b2v[4], W3v[4];
  uint32_t gb1v[4], gb2v[4];
  #pragma unroll
  for (int jt = 0; jt < 4; ++jt) {
    int n = ln + 16 * jt;
    b1v[jt] = b1[n];  b2v[jt] = b2[n];  W3v[jt] = W3[n];
    gb1v[jt] = ((uint32_t)(unsigned short)bf16rne(g1[n]) << 16)
             | (unsigned short)bf16rne(be1[n]);
    gb2v[jt] = ((uint32_t)(unsigned short)bf16rne(g2[n]) << 16)
             | (unsigned short)bf16rne(be2[n]);
  }
  const float b3s = b3[0];

  const bool idx64 = (__ballot(ei[2 * lane + 1] == 0) == ~0ull);

  int sI[4], dI[4], sN[4], dN[4];
  {
    const int eb0 = blockIdx.x * 256 + wv * 64;
    #pragma unroll
    for (int mt = 0; mt < 4; ++mt) {
      int el = eb0 + mt * 16 + ln;
      int ec = el < E ? el : E - 1;
      if (idx64) { sI[mt] = ei[2 * ec]; dI[mt] = ei[2 * (E + ec)]; }
      else       { sI[mt] = ei[ec];     dI[mt] = ei[E + ec]; }
      sN[mt] = sI[mt]; dN[mt] = dI[mt];
    }
  }

  // ---- double-buffered gather banks: nf frags land as bf16 directly ----
  short8 gbank[2][4];     // [bank][t: src0,src1,dst0,dst1]
  f32x4  ebank[2][2];     // [bank][ea half]
  auto issueG = [&](int bank, int s, int d, int el) {
    int ec = el < E ? el : E - 1;
    const unsigned short* sp = nfb + (size_t)s * 64 + quad * 8;
    const unsigned short* dp = nfb + (size_t)d * 64 + quad * 8;
    const float* ap = ea + (size_t)ec * 16 + (quad & 1) * 8;
    gbank[bank][0] = *(const short8*)sp;
    gbank[bank][1] = *(const short8*)(sp + 32);
    gbank[bank][2] = *(const short8*)dp;
    gbank[bank][3] = *(const short8*)(dp + 32);
    ebank[bank][0] = *(const f32x4*)ap;
    ebank[bank][1] = *(const f32x4*)(ap + 4);
  };

  issueG(0, sI[0], dI[0], blockIdx.x * 256 + wv * 64 + ln);

  for (int tile = blockIdx.x; tile < ntiles; tile += gridDim.x) {
    const int ebase = tile * 256 + wv * 64;

    #pragma unroll
    for (int mt = 0; mt < 4; ++mt) {
      const int cur = mt & 1, nxt = cur ^ 1;

      // ea -> bf16 fragment (only remaining conversion)
      short8 afr4 = cvt8(ebank[cur][0], ebank[cur][1]);

      // ---- Layer 1: 20 MFMAs ----
      f32x4 acc[4];
      #pragma unroll
      for (int jt = 0; jt < 4; ++jt) acc[jt] = (f32x4)(b1v[jt]);

      #pragma unroll
      for (int t = 0; t < 5; ++t) {
        short8 af = (t < 4) ? gbank[cur][t] : afr4;   // folds at unroll
        #pragma unroll
        for (int jt = 0; jt < 4; ++jt) {
          short8 bfr = *(const short8*)&W1T[(jt * 16 + ln) * SW1 + t * 32 + quad * 8];
          acc[jt] = __builtin_amdgcn_mfma_f32_16x16x32_bf16(
              af, bfr, acc[jt], 0, 0, 0);
        }
      }

      // ---- Prefetch next tile's indices (consumed at mt==3) ----
      if (mt == 1) {
        int ntile = tile + gridDim.x;
        if (ntile < ntiles) {
          const int nb = ntile * 256 + wv * 64;
          #pragma unroll
          for (int m2 = 0; m2 < 4; ++m2) {
            int el = nb + m2 * 16 + ln;
            int ec = el < E ? el : E - 1;
            if (idx64) { sN[m2] = ei[2 * ec]; dN[m2] = ei[2 * (E + ec)]; }
            else       { sN[m2] = ei[ec];     dN[m2] = ei[E + ec]; }
          }
        }
      }

      // ---- Issue next mt's gather into the other bank ----
      if (mt < 3) issueG(nxt, sI[mt + 1], dI[mt + 1], ebase + (mt + 1) * 16 + ln);
      else        issueG(nxt, sN[0], dN[0], (tile + (int)gridDim.x) * 256 + wv * 64 + ln);

      // ---- Epilogue (wave-private; DPP reductions, no walls) ----
      f32x4 mu, rs;
      lnstats(acc[0], acc[1], acc[2], acc[3], mu, rs);

      #pragma unroll
      for (int jt = 0; jt < 4; ++jt) {
        float gA = bf(gb1v[jt] & 0xffff0000u);
        float bA = bf((uint32_t)(gb1v[jt] << 16));
        #pragma unroll
        for (int r = 0; r < 4; ++r) {
          float h = (acc[jt][r] - mu[r]) * rs[r] * gA + bA;
          h = fmaxf(h, NEG_SLOPE * h);
          HB[wv][(quad * 4 + r) * SW2 + ln + 16 * jt] = (short)cvtpk(h, h);
        }
      }
      // no lgkmcnt(0) wall (r17: DS in-order per wave; proven)

      f32x4 acc2[4];
      #pragma unroll
      for (int jt = 0; jt < 4; ++jt) acc2[jt] = (f32x4)(b2v[jt]);
      #pragma unroll
      for (int t2 = 0; t2 < 2; ++t2) {
        short8 a2 = *(const short8*)&HB[wv][ln * SW2 + t2 * 32 + quad * 8];
        #pragma unroll
        for (int jt = 0; jt < 4; ++jt) {
          short8 w2f = *(const short8*)&W2T[(jt * 16 + ln) * SW2 + t2 * 32 + quad * 8];
          acc2[jt] = __builtin_amdgcn_mfma_f32_16x16x32_bf16(
              a2, w2f, acc2[jt], 0, 0, 0);
        }
      }

      f32x4 mu2, rs2;
      lnstats(acc2[0], acc2[1], acc2[2], acc2[3], mu2, rs2);

      f32x4 po = (f32x4)0.f;
      #pragma unroll
      for (int jt = 0; jt < 4; ++jt) {
        float gA = bf(gb2v[jt] & 0xffff0000u);
        float bA = bf((uint32_t)(gb2v[jt] << 16));
        #pragma unroll
        for (int r = 0; r < 4; ++r) {
          float h = (acc2[jt][r] - mu2[r]) * rs2[r] * gA + bA;
          h = fmaxf(h, NEG_SLOPE * h);
          po[r] = fmaf(h, W3v[jt], po[r]);
        }
      }
      redsum16(po);

      if (ln < 4) {
        int e = ebase + mt * 16 + quad * 4 + ln;
        if (e < E) {
          float v = (ln == 0) ? po[0] : (ln == 1) ? po[1]
                  : (ln == 2) ? po[2] : po[3];
          out[e] = v + b3s;
        }
      }
    }

    #pragma unroll
    for (int m2 = 0; m2 < 4; ++m2) { sI[m2] = sN[m2]; dI[m2] = dN[m2]; }
  }
}

// ================= fallback: r17 kernel (f32 gather, bound 3) =================
__global__ __launch_bounds__(TPB, 3)
void edge_mlp_mfma_f32(const float* __restrict__ nf, const int* __restrict__ ei,
                       const float* __restrict__ ea,
                       const float* __restrict__ W1, const float* __restrict__ b1,
                       const float* __restrict__ g1, const float* __restrict__ be1,
                       const float* __restrict__ W2, const float* __restrict__ b2,
                       const float* __restrict__ g2, const float* __restrict__ be2,
                       const float* __restrict__ W3, const float* __restrict__ b3,
                       float* __restrict__ out, int E, int ntiles) {
  __shared__ short W1T[64 * SW1];
  __shared__ short W2T[64 * SW2];
  __shared__ short HB[4][16 * SW2];

  const int tid  = threadIdx.x;
  const int lane = tid & 63;
  const int wv   = tid >> 6;
  const int ln   = lane & 15;
  const int quad = lane >> 4;

  for (int i = tid; i < 9216; i += TPB) {
    int n = i & 63, k = i >> 6;
    W1T[n * SW1 + k] = bf16rne(W1[k * 64 + n]);
  }
  for (int i = tid; i < 1024; i += TPB) {
    int n = i & 63, k = 144 + (i >> 6);
    W1T[n * SW1 + k] = 0;
  }
  for (int i = tid; i < 4096; i += TPB) {
    int n = i & 63, k = i >> 6;
    W2T[n * SW2 + k] = bf16rne(W2[k * 64 + n]);
  }
  __syncthreads();

  float b1v[4], g1v[4], be1v[4], b2v[4], g2v[4], be2v[4], W3v[4];
  #pragma unroll
  for (int jt = 0; jt < 4; ++jt) {
    int n = ln + 16 * jt;
    b1v[jt] = b1[n];  g1v[jt] = g1[n];  be1v[jt] = be1[n];
    b2v[jt] = b2[n];  g2v[jt] = g2[n];  be2v[jt] = be2[n];
    W3v[jt] = W3[n];
  }
  const float b3s = b3[0];

  const bool idx64 = (__ballot(ei[2 * lane + 1] == 0) == ~0ull);

  int sI[4], dI[4], sN[4], dN[4];
  {
    const int eb0 = blockIdx.x * 256 + wv * 64;
    #pragma unroll
    for (int mt = 0; mt < 4; ++mt) {
      int el = eb0 + mt * 16 + ln;
      int ec = el < E ? el : E - 1;
      if (idx64) { sI[mt] = ei[2 * ec]; dI[mt] = ei[2 * (E + ec)]; }
      else       { sI[mt] = ei[ec];     dI[mt] = ei[E + ec]; }
      sN[mt] = sI[mt]; dN[mt] = dI[mt];
    }
  }

  f32x4 raw[10];
  auto issue = [&](int s, int d, int el) {
    int ec = el < E ? el : E - 1;
    const float* sp = nf + (size_t)s * 64 + quad * 8;
    const float* dp = nf + (size_t)d * 64 + quad * 8;
    const float* ap = ea + (size_t)ec * 16 + (quad & 1) * 8;
    raw[0] = *(const f32x4*)sp;        raw[1] = *(const f32x4*)(sp + 4);
    raw[2] = *(const f32x4*)(sp + 32); raw[3] = *(const f32x4*)(sp + 36);
    raw[4] = *(const f32x4*)dp;        raw[5] = *(const f32x4*)(dp + 4);
    raw[6] = *(const f32x4*)(dp + 32); raw[7] = *(const f32x4*)(dp + 36);
    raw[8] = *(const f32x4*)ap;        raw[9] = *(const f32x4*)(ap + 4);
  };

  issue(sI[0], dI[0], blockIdx.x * 256 + wv * 64 + ln);

  for (int tile = blockIdx.x; tile < ntiles; tile += gridDim.x) {
    const int ebase = tile * 256 + wv * 64;

    #pragma unroll
    for (int mt = 0; mt < 4; ++mt) {
      short8 afr[5];
      afr[0] = cvt8(raw[0], raw[1]);
      afr[1] = cvt8(raw[2], raw[3]);
      afr[2] = cvt8(raw[4], raw[5]);
      afr[3] = cvt8(raw[6], raw[7]);
      afr[4] = cvt8(raw[8], raw[9]);

      f32x4 acc[4];
      #pragma unroll
      for (int jt = 0; jt < 4; ++jt) acc[jt] = (f32x4)(b1v[jt]);

      #pragma unroll
      for (int t = 0; t < 5; ++t)
        #pragma unroll
        for (int jt = 0; jt < 4; ++jt) {
          short8 bfr = *(const short8*)&W1T[(jt * 16 + ln) * SW1 + t * 32 + quad * 8];
          acc[jt] = __builtin_amdgcn_mfma_f32_16x16x32_bf16(
              afr[t], bfr, acc[jt], 0, 0, 0);
        }

      if (mt == 1) {
        int ntile = tile + gridDim.x;
        if (ntile < ntiles) {
          const int nb = ntile * 256 + wv * 64;
          #pragma unroll
          for (int m2 = 0; m2 < 4; ++m2) {
            int el = nb + m2 * 16 + ln;
            int ec = el < E ? el : E - 1;
            if (idx64) { sN[m2] = ei[2 * ec]; dN[m2] = ei[2 * (E + ec)]; }
            else       { sN[m2] = ei[ec];     dN[m2] = ei[E + ec]; }
          }
        }
      }

      if (mt < 3) issue(sI[mt + 1], dI[mt + 1], ebase + (mt + 1) * 16 + ln);
      else        issue(sN[0], dN[0], (tile + (int)gridDim.x) * 256 + wv * 64 + ln);

      f32x4 mu, rs;
      lnstats(acc[0], acc[1], acc[2], acc[3], mu, rs);

      #pragma unroll
      for (int jt = 0; jt < 4; ++jt)
        #pragma unroll
        for (int r = 0; r < 4; ++r) {
          float h = (acc[jt][r] - mu[r]) * rs[r] * g1v[jt] + be1v[jt];
          h = fmaxf(h, NEG_SLOPE * h);
          HB[wv][(quad * 4 + r) * SW2 + ln + 16 * jt] = (short)cvtpk(h, h);
        }

      f32x4 acc2[4];
      #pragma unroll
      for (int jt = 0; jt < 4; ++jt) acc2[jt] = (f32x4)(b2v[jt]);
      #pragma unroll
      for (int t2 = 0; t2 < 2; ++t2) {
        short8 a2 = *(const short8*)&HB[wv][ln * SW2 + t2 * 32 + quad * 8];
        #pragma unroll
        for (int jt = 0; jt < 4; ++jt) {
          short8 w2f = *(const short8*)&W2T[(jt * 16 + ln) * SW2 + t2 * 32 + quad * 8];
          acc2[jt] = __builtin_amdgcn_mfma_f32_16x16x32_bf16(
              a2, w2f, acc2[jt], 0, 0, 0);
        }
      }

      f32x4 mu2, rs2;
      lnstats(acc2[0], acc2[1], acc2[2], acc2[3], mu2, rs2);

      f32x4 po = (f32x4)0.f;
      #pragma unroll
      for (int jt = 0; jt < 4; ++jt)
        #pragma unroll
        for (int r = 0; r < 4; ++r) {
          float h = (acc2[jt][r] - mu2[r]) * rs2[r] * g2v[jt] + be2v[jt];
          h = fmaxf(h, NEG_SLOPE * h);
          po[r] = fmaf(h, W3v[jt], po[r]);
        }
      redsum16(po);

      if (ln < 4) {
        int e = ebase + mt * 16 + quad * 4 + ln;
        if (e < E) {
          float v = (ln == 0) ? po[0] : (ln == 1) ? po[1]
                  : (ln == 2) ? po[2] : po[3];
          out[e] = v + b3s;
        }
      }
    }

    #pragma unroll
    for (int m2 = 0; m2 < 4; ++m2) { sI[m2] = sN[m2]; dI[m2] = dN[m2]; }
  }
}

extern "C" void kernel_launch(void* const* d_in, const int* in_sizes, int n_in,
                              void* d_out, int out_size, void* d_ws, size_t ws_size,
                              hipStream_t stream) {
  const float* nf = (const float*)d_in[0];
  const int*   ei = (const int*)d_in[1];
  const float* ea = (const float*)d_in[2];

  const int E = out_size;
  const int ntiles = (E + 255) / 256;
  const int blocks = ntiles < 2048 ? ntiles : 2048;

  const size_t nfElems = (size_t)in_sizes[0];          // n_nodes * 64
  const bool useWS = (d_ws != nullptr) &&
                     (ws_size >= nfElems * sizeof(unsigned short));

  if (useWS) {
    const int cblk = (int)((nfElems / 8 + 255) / 256);
    cvt_nf<<<cblk, 256, 0, stream>>>(nf, (unsigned short*)d_ws, (int)nfElems);
    edge_mlp_mfma_bf<<<blocks, TPB, 0, stream>>>(
        (const unsigned short*)d_ws, ei, ea,
        (const float*)d_in[3],  (const float*)d_in[4],
        (const float*)d_in[5],  (const float*)d_in[6],
        (const float*)d_in[7],  (const float*)d_in[8],
        (const float*)d_in[9],  (const float*)d_in[10],
        (const float*)d_in[11], (const float*)d_in[12],
        (float*)d_out, E, ntiles);
  } else {
    edge_mlp_mfma_f32<<<blocks, TPB, 0, stream>>>(
        nf, ei, ea,
        (const float*)d_in[3],  (const float*)d_in[4],
        (const float*)d_in[5],  (const float*)d_in[6],
        (const float*)d_in[7],  (const float*)d_in[8],
        (const float*)d_in[9],  (const float*)d_in[10],
        (const float*)d_in[11], (const float*)d_in[12],
        (float*)d_out, E, ntiles);
  }
}